// Round 6
// baseline (284.075 us; speedup 1.0000x reference)
//
#include <hip/hip_runtime.h>

// RelScaleAttend: b=4, 16 heads, s=1024 (32x32 img), d=64.
// Kernel 1 (pack): K fp32 -> Kp bf16 row-major [bh][key][c]; V fp32 -> Vt bf16
//   transposed [bh][d][key]. Makes MFMA A-fragments of K and V^T direct 16B
//   global loads in the attention kernel.
// Kernel 2 (attn): per block 64 queries (4 waves x 16), K-tile = 32 keys.
//   Computes S^T = mfma(A=K, B=Q) so each lane owns ONE query: softmax is
//   per-lane (no shuffles in loop), P round-trip is per-wave LDS (no barrier).
//   Main loop has ZERO barriers. Static-max softmax (M = max_kh + max_kw,
//   exact shift, validated R3-R5). Exact fp32 rel tables in prologue.

#define SCALE2 0.18033688f   // 0.125 * log2(e)
#define LOG2E  1.44269504f

typedef float  f32x4  __attribute__((ext_vector_type(4)));
typedef __bf16 bf16x8 __attribute__((ext_vector_type(8)));
typedef __bf16 bf16x4 __attribute__((ext_vector_type(4)));

// ---------------- kernel 1: pack K, transpose+pack V ----------------
__global__ __launch_bounds__(256) void pack(
        const float* __restrict__ kg, const float* __restrict__ vg,
        __bf16* __restrict__ Kp, __bf16* __restrict__ Vt) {
    __shared__ float Vl[64 * 65];          // stride 65: conflict-free transpose
    const int t = threadIdx.x;
    const int kb = blockIdx.x, bh = blockIdx.y;
    const int bb = bh >> 4, nh = bh & 15;
    const int row = t >> 2, cseg = (t & 3) << 4;
    const float* gsrc_base = (const float*)nullptr;
    const size_t goff = (size_t)bb * 1048576 + nh * 64
                      + (size_t)(kb * 64 + row) * 1024 + cseg;
    (void)gsrc_base;
    {   // K: read 16 fp32, write 16 bf16 (row-major, unchanged layout)
        const float* kp = kg + goff;
        f32x4 a = ((const f32x4*)kp)[0], b = ((const f32x4*)kp)[1],
              c = ((const f32x4*)kp)[2], d = ((const f32x4*)kp)[3];
        bf16x8 t0, t1;
        t0[0]=(__bf16)a.x; t0[1]=(__bf16)a.y; t0[2]=(__bf16)a.z; t0[3]=(__bf16)a.w;
        t0[4]=(__bf16)b.x; t0[5]=(__bf16)b.y; t0[6]=(__bf16)b.z; t0[7]=(__bf16)b.w;
        t1[0]=(__bf16)c.x; t1[1]=(__bf16)c.y; t1[2]=(__bf16)c.z; t1[3]=(__bf16)c.w;
        t1[4]=(__bf16)d.x; t1[5]=(__bf16)d.y; t1[6]=(__bf16)d.z; t1[7]=(__bf16)d.w;
        __bf16* o = Kp + bh * 65536 + (kb * 64 + row) * 64 + cseg;
        *(bf16x8*)o = t0; *(bf16x8*)(o + 8) = t1;
    }
    {   // V: coalesced read -> LDS
        const float* vp = vg + goff;
        f32x4 a = ((const f32x4*)vp)[0], b = ((const f32x4*)vp)[1],
              c = ((const f32x4*)vp)[2], d = ((const f32x4*)vp)[3];
        float* dst = &Vl[row * 65 + cseg];
        dst[0]=a.x; dst[1]=a.y; dst[2]=a.z; dst[3]=a.w;
        dst[4]=b.x; dst[5]=b.y; dst[6]=b.z; dst[7]=b.w;
        dst[8]=c.x; dst[9]=c.y; dst[10]=c.z; dst[11]=c.w;
        dst[12]=d.x; dst[13]=d.y; dst[14]=d.z; dst[15]=d.w;
    }
    __syncthreads();
    {   // transpose out: this thread owns d = row, keys cseg..cseg+15
        bf16x8 o0, o1;
#pragma unroll
        for (int j = 0; j < 8; ++j) o0[j] = (__bf16)Vl[(cseg + j) * 65 + row];
#pragma unroll
        for (int j = 0; j < 8; ++j) o1[j] = (__bf16)Vl[(cseg + 8 + j) * 65 + row];
        __bf16* o = Vt + bh * 65536 + row * 1024 + kb * 64 + cseg;
        *(bf16x8*)o = o0; *(bf16x8*)(o + 8) = o1;
    }
}

// ---------------- kernel 2: barrier-free flash attention ----------------
__global__ __launch_bounds__(256, 4) void attn(
        const float* __restrict__ qg,
        const float* __restrict__ rph, const float* __restrict__ rpw,
        const __bf16* __restrict__ Kp, const __bf16* __restrict__ Vt,
        float* __restrict__ outg) {
    // LDS = 8448 + 8448 + 1024 + 17408 = 35328 B -> 4 blocks/CU.
    __shared__ float RelH[64 * 33];
    __shared__ float RelW[64 * 33];
    __shared__ float MH[4 * 64];
    __shared__ __align__(16) char arena[17408];
    float*  Ql = (float*)arena;            // prologue: 64 x 68 fp32
    __bf16* Pw = (__bf16*)arena;           // loop: 4 waves x (16 x 36) bf16

    const int tid  = threadIdx.x;
    const int w    = tid >> 6, lane = tid & 63;
    const int quad = lane >> 4, n16 = lane & 15;
    const int hp = blockIdx.x, bh = blockIdx.y;
    const int bb = bh >> 4, nh = bh & 15;
    const int h0 = hp << 1;
    const int base = bb * 1048576 + nh * 64;
    const int sq0  = h0 * 32;

    // ---- stage Q rows (fp32) into LDS, coalesced b128 ----
    {
        int r0 = tid >> 4, c0 = (tid & 15) << 2;
#pragma unroll
        for (int k2 = 0; k2 < 4; ++k2) {
            int row = k2 * 16 + r0;
            *(f32x4*)&Ql[row * 68 + c0] =
                *(const f32x4*)(qg + base + (sq0 + row) * 1024 + c0);
        }
    }
    __syncthreads();

    // ---- prologue: exact fp32 rel tables (x log2e) + slot maxes ----
    {
        int ql = tid & 63, slot = tid >> 6;
        int isw = slot >> 1, khb = (slot & 1) << 4;
        int hh = h0 + (ql >> 5), wl = ql & 31;
        int row0 = (isw ? wl : hh) + 31 - khb;      // row_j = row0 - j, in-bounds
        const float* tp = (isw ? rpw : rph) + row0 * 64;
        const float* qrow = &Ql[ql * 68];
        float acc[16];
#pragma unroll
        for (int j = 0; j < 16; ++j) acc[j] = 0.f;
#pragma unroll 4
        for (int cq = 0; cq < 16; ++cq) {
            f32x4 qv = *(const f32x4*)(qrow + cq * 4);
#pragma unroll
            for (int j = 0; j < 16; ++j) {
                f32x4 tv = *(const f32x4*)(tp - j * 64 + cq * 4);
                acc[j] += qv.x * tv.x + qv.y * tv.y + qv.z * tv.z + qv.w * tv.w;
            }
        }
        float* dst = (isw ? RelW : RelH) + ql * 33 + khb;
        float hmax = -1e30f;
#pragma unroll
        for (int j = 0; j < 16; ++j) {
            float v = acc[j] * LOG2E;
            dst[j] = v;
            hmax = fmaxf(hmax, v);
        }
        MH[slot * 64 + ql] = hmax;
    }

    // ---- Q fragment (B-operand for S^T): holds Q[q=n16][c=ch*32+quad*8+j] ----
    const int q = w * 16 + n16;                 // this lane's local query
    bf16x8 qf[2];
#pragma unroll
    for (int ch = 0; ch < 2; ++ch) {
        const float* qp = &Ql[q * 68 + ch * 32 + quad * 8];
        f32x4 a = ((const f32x4*)qp)[0];
        f32x4 b = ((const f32x4*)qp)[1];
        bf16x8 t;
        t[0] = (__bf16)a.x; t[1] = (__bf16)a.y; t[2] = (__bf16)a.z; t[3] = (__bf16)a.w;
        t[4] = (__bf16)b.x; t[5] = (__bf16)b.y; t[6] = (__bf16)b.z; t[7] = (__bf16)b.w;
        qf[ch] = t;
    }
    __syncthreads();     // tables + MH ready; Ql dead -> arena becomes Pw
    // ---------------- NO MORE BARRIERS BELOW ----------------

    // per-lane static max M; rel_w (tile-invariant, kw = g*16 + quad*4 + r)
    float rwm[8];
    {
        float M = fmaxf(MH[q], MH[64 + q]) + fmaxf(MH[128 + q], MH[192 + q]);
#pragma unroll
        for (int g = 0; g < 2; ++g)
#pragma unroll
            for (int r = 0; r < 4; ++r)
                rwm[g * 4 + r] = RelW[q * 33 + g * 16 + quad * 4 + r] - M;
    }

    float lr = 0.f;
    f32x4 oc[4];
#pragma unroll
    for (int i = 0; i < 4; ++i) oc[i] = (f32x4){0.f, 0.f, 0.f, 0.f};

    const __bf16* KpH = Kp + bh * 65536;
    const __bf16* VtH = Vt + bh * 65536;
    __bf16* Pme = Pw + w * 576;            // this wave's 16x36 P tile

    // K fragments for tile 0 (A-operand: K[key = kt*32+g*16+n16][c])
    bf16x8 kc[2][2];
#pragma unroll
    for (int g = 0; g < 2; ++g)
#pragma unroll
        for (int ch = 0; ch < 2; ++ch)
            kc[g][ch] = *(const bf16x8*)(KpH + (g * 16 + n16) * 64 + ch * 32 + quad * 8);

    for (int kt = 0; kt < 32; ++kt) {
        // prefetch next tile's K fragments (consumed next iteration)
        bf16x8 kn[2][2];
        if (kt < 31) {
#pragma unroll
            for (int g = 0; g < 2; ++g)
#pragma unroll
                for (int ch = 0; ch < 2; ++ch)
                    kn[g][ch] = *(const bf16x8*)(KpH + ((kt + 1) * 32 + g * 16 + n16) * 64
                                                 + ch * 32 + quad * 8);
        }
        // V^T fragments for this tile (used after softmax — natural cover)
        bf16x8 vf[4];
#pragma unroll
        for (int cn = 0; cn < 4; ++cn)
            vf[cn] = *(const bf16x8*)(VtH + (cn * 16 + n16) * 1024 + kt * 32 + quad * 8);

        float rh = RelH[q * 33 + kt];

        // S^T = K Q^T : lane gets S[q=n16][key = g*16 + quad*4 + r]
        f32x4 s0 = {0.f, 0.f, 0.f, 0.f}, s1 = s0;
#pragma unroll
        for (int ch = 0; ch < 2; ++ch) {
            s0 = __builtin_amdgcn_mfma_f32_16x16x32_bf16(kc[0][ch], qf[ch], s0, 0, 0, 0);
            s1 = __builtin_amdgcn_mfma_f32_16x16x32_bf16(kc[1][ch], qf[ch], s1, 0, 0, 0);
        }

        // per-lane softmax (static max), P write in B-layout rows
        bf16x4 pb0, pb1;
        float ps = 0.f;
#pragma unroll
        for (int r = 0; r < 4; ++r) {
            float p0 = exp2f(fmaf(s0[r], SCALE2, rh + rwm[r]));
            float p1 = exp2f(fmaf(s1[r], SCALE2, rh + rwm[4 + r]));
            ps += p0 + p1;
            pb0[r] = (__bf16)p0; pb1[r] = (__bf16)p1;
        }
        lr += ps;
        *(bf16x4*)&Pme[n16 * 36 + quad * 4]      = pb0;
        *(bf16x4*)&Pme[n16 * 36 + 16 + quad * 4] = pb1;

        // O^T += V^T P : B-frag = P[q=n16][k=quad*8+j] (same-wave LDS, no barrier)
        bf16x8 pf = *(const bf16x8*)&Pme[n16 * 36 + quad * 8];
#pragma unroll
        for (int cn = 0; cn < 4; ++cn)
            oc[cn] = __builtin_amdgcn_mfma_f32_16x16x32_bf16(vf[cn], pf, oc[cn], 0, 0, 0);

        if (kt < 31) {
#pragma unroll
            for (int g = 0; g < 2; ++g)
#pragma unroll
                for (int ch = 0; ch < 2; ++ch)
                    kc[g][ch] = kn[g][ch];
        }
    }

    // ---- epilogue: quad-reduce l (lanes differing in bits 4..5), store ----
    lr += __shfl_xor(lr, 16);
    lr += __shfl_xor(lr, 32);
    float inv = 1.f / lr;
    float* orow = outg + base + (sq0 + q) * 1024;
#pragma unroll
    for (int cn = 0; cn < 4; ++cn) {
        f32x4 v = oc[cn];
        v.x *= inv; v.y *= inv; v.z *= inv; v.w *= inv;
        *(f32x4*)(orow + cn * 16 + quad * 4) = v;
    }
}

extern "C" void kernel_launch(void* const* d_in, const int* in_sizes, int n_in,
                              void* d_out, int out_size, void* d_ws, size_t ws_size,
                              hipStream_t stream) {
    (void)in_sizes; (void)n_in; (void)out_size; (void)ws_size;
    const float* q   = (const float*)d_in[0];
    const float* k   = (const float*)d_in[1];
    const float* v   = (const float*)d_in[2];
    const float* rph = (const float*)d_in[3];
    const float* rpw = (const float*)d_in[4];
    __bf16* Kp = (__bf16*)d_ws;                 // 64*1024*64 bf16 = 8 MB
    __bf16* Vt = Kp + 64 * 65536;               // + 8 MB

    dim3 g(16, 64);                             // (key-block / h-pair, bh)
    pack<<<g, 256, 0, stream>>>(k, v, Kp, Vt);
    attn<<<g, 256, 0, stream>>>(q, rph, rpw, Kp, Vt, (float*)d_out);
}

// Round 7
// 279.583 us; speedup vs baseline: 1.0161x; 1.0161x over previous
//
#include <hip/hip_runtime.h>

// RelScaleAttend: b=4, 16 heads, s=1024 (32x32 img), d=64.
// Kernel 1 (pack): K fp32 -> Kp bf16 row-major [bh][key][c]; V fp32 -> Vt bf16
//   transposed [bh][d][key]. Makes MFMA fragments of K and V^T direct 16B
//   global loads in the attention kernel.
// Kernel 2 (attn): per block 64 queries (4 waves x 16), K-tile = 32 keys.
//   S^T = mfma(A=K, B=Q): each lane owns ONE query -> per-lane softmax,
//   per-wave P LDS round-trip, ZERO barriers in the main loop.
//   Static-max softmax (M = max_kh + max_kw, exact shift, validated R3-R6).
//   K and V fragments for tile kt+1 are register-prefetched at top of iter kt.
//   launch_bounds(256,3): ~168 VGPR cap -- (256,4)'s 64-VGPR cap spilled
//   (R5/R6: +50MB FETCH, +18MB WRITE scratch traffic). Do not tighten.

#define SCALE2 0.18033688f   // 0.125 * log2(e)
#define LOG2E  1.44269504f

typedef float  f32x4  __attribute__((ext_vector_type(4)));
typedef __bf16 bf16x8 __attribute__((ext_vector_type(8)));
typedef __bf16 bf16x4 __attribute__((ext_vector_type(4)));

// ---------------- kernel 1: pack K, transpose+pack V ----------------
__global__ __launch_bounds__(256) void pack(
        const float* __restrict__ kg, const float* __restrict__ vg,
        __bf16* __restrict__ Kp, __bf16* __restrict__ Vt) {
    __shared__ float Vl[64 * 65];          // stride 65: conflict-free transpose
    const int t = threadIdx.x;
    const int kb = blockIdx.x, bh = blockIdx.y;
    const int bb = bh >> 4, nh = bh & 15;
    const int row = t >> 2, cseg = (t & 3) << 4;
    const size_t goff = (size_t)bb * 1048576 + nh * 64
                      + (size_t)(kb * 64 + row) * 1024 + cseg;
    {   // K: read 16 fp32, write 16 bf16 (row-major, unchanged layout)
        const float* kp = kg + goff;
        f32x4 a = ((const f32x4*)kp)[0], b = ((const f32x4*)kp)[1],
              c = ((const f32x4*)kp)[2], d = ((const f32x4*)kp)[3];
        bf16x8 t0, t1;
        t0[0]=(__bf16)a.x; t0[1]=(__bf16)a.y; t0[2]=(__bf16)a.z; t0[3]=(__bf16)a.w;
        t0[4]=(__bf16)b.x; t0[5]=(__bf16)b.y; t0[6]=(__bf16)b.z; t0[7]=(__bf16)b.w;
        t1[0]=(__bf16)c.x; t1[1]=(__bf16)c.y; t1[2]=(__bf16)c.z; t1[3]=(__bf16)c.w;
        t1[4]=(__bf16)d.x; t1[5]=(__bf16)d.y; t1[6]=(__bf16)d.z; t1[7]=(__bf16)d.w;
        __bf16* o = Kp + bh * 65536 + (kb * 64 + row) * 64 + cseg;
        *(bf16x8*)o = t0; *(bf16x8*)(o + 8) = t1;
    }
    {   // V: coalesced read -> LDS
        const float* vp = vg + goff;
        f32x4 a = ((const f32x4*)vp)[0], b = ((const f32x4*)vp)[1],
              c = ((const f32x4*)vp)[2], d = ((const f32x4*)vp)[3];
        float* dst = &Vl[row * 65 + cseg];
        dst[0]=a.x; dst[1]=a.y; dst[2]=a.z; dst[3]=a.w;
        dst[4]=b.x; dst[5]=b.y; dst[6]=b.z; dst[7]=b.w;
        dst[8]=c.x; dst[9]=c.y; dst[10]=c.z; dst[11]=c.w;
        dst[12]=d.x; dst[13]=d.y; dst[14]=d.z; dst[15]=d.w;
    }
    __syncthreads();
    {   // transpose out: this thread owns d = row, keys cseg..cseg+15
        bf16x8 o0, o1;
#pragma unroll
        for (int j = 0; j < 8; ++j) o0[j] = (__bf16)Vl[(cseg + j) * 65 + row];
#pragma unroll
        for (int j = 0; j < 8; ++j) o1[j] = (__bf16)Vl[(cseg + 8 + j) * 65 + row];
        __bf16* o = Vt + bh * 65536 + row * 1024 + kb * 64 + cseg;
        *(bf16x8*)o = o0; *(bf16x8*)(o + 8) = o1;
    }
}

// ---------------- kernel 2: barrier-free flash attention ----------------
__global__ __launch_bounds__(256, 3) void attn(
        const float* __restrict__ qg,
        const float* __restrict__ rph, const float* __restrict__ rpw,
        const __bf16* __restrict__ Kp, const __bf16* __restrict__ Vt,
        float* __restrict__ outg) {
    // LDS = 8448 + 8448 + 1024 + 17408 = 35328 B.
    __shared__ float RelH[64 * 33];
    __shared__ float RelW[64 * 33];
    __shared__ float MH[4 * 64];
    __shared__ __align__(16) char arena[17408];
    float*  Ql = (float*)arena;            // prologue: 64 x 68 fp32
    __bf16* Pw = (__bf16*)arena;           // loop: 4 waves x (16 x 36) bf16

    const int tid  = threadIdx.x;
    const int w    = tid >> 6, lane = tid & 63;
    const int quad = lane >> 4, n16 = lane & 15;
    const int hp = blockIdx.x, bh = blockIdx.y;
    const int bb = bh >> 4, nh = bh & 15;
    const int h0 = hp << 1;
    const int base = bb * 1048576 + nh * 64;
    const int sq0  = h0 * 32;

    // ---- stage Q rows (fp32) into LDS, coalesced b128 ----
    {
        int r0 = tid >> 4, c0 = (tid & 15) << 2;
#pragma unroll
        for (int k2 = 0; k2 < 4; ++k2) {
            int row = k2 * 16 + r0;
            *(f32x4*)&Ql[row * 68 + c0] =
                *(const f32x4*)(qg + base + (sq0 + row) * 1024 + c0);
        }
    }
    __syncthreads();

    // ---- prologue: exact fp32 rel tables (x log2e) + slot maxes ----
    {
        int ql = tid & 63, slot = tid >> 6;
        int isw = slot >> 1, khb = (slot & 1) << 4;
        int hh = h0 + (ql >> 5), wl = ql & 31;
        int row0 = (isw ? wl : hh) + 31 - khb;      // row_j = row0 - j, in-bounds
        const float* tp = (isw ? rpw : rph) + row0 * 64;
        const float* qrow = &Ql[ql * 68];
        float acc[16];
#pragma unroll
        for (int j = 0; j < 16; ++j) acc[j] = 0.f;
#pragma unroll 4
        for (int cq = 0; cq < 16; ++cq) {
            f32x4 qv = *(const f32x4*)(qrow + cq * 4);
#pragma unroll
            for (int j = 0; j < 16; ++j) {
                f32x4 tv = *(const f32x4*)(tp - j * 64 + cq * 4);
                acc[j] += qv.x * tv.x + qv.y * tv.y + qv.z * tv.z + qv.w * tv.w;
            }
        }
        float* dst = (isw ? RelW : RelH) + ql * 33 + khb;
        float hmax = -1e30f;
#pragma unroll
        for (int j = 0; j < 16; ++j) {
            float v = acc[j] * LOG2E;
            dst[j] = v;
            hmax = fmaxf(hmax, v);
        }
        MH[slot * 64 + ql] = hmax;
    }

    // ---- Q fragment (B-operand for S^T): Q[q=n16][c=ch*32+quad*8+j] ----
    const int q = w * 16 + n16;                 // this lane's local query
    bf16x8 qf[2];
#pragma unroll
    for (int ch = 0; ch < 2; ++ch) {
        const float* qp = &Ql[q * 68 + ch * 32 + quad * 8];
        f32x4 a = ((const f32x4*)qp)[0];
        f32x4 b = ((const f32x4*)qp)[1];
        bf16x8 t;
        t[0] = (__bf16)a.x; t[1] = (__bf16)a.y; t[2] = (__bf16)a.z; t[3] = (__bf16)a.w;
        t[4] = (__bf16)b.x; t[5] = (__bf16)b.y; t[6] = (__bf16)b.z; t[7] = (__bf16)b.w;
        qf[ch] = t;
    }
    __syncthreads();     // tables + MH ready; Ql dead -> arena becomes Pw
    // ---------------- NO MORE BARRIERS BELOW ----------------

    // per-lane static max M; rel_w (tile-invariant, kw = g*16 + quad*4 + r)
    float rwm[8];
    {
        float M = fmaxf(MH[q], MH[64 + q]) + fmaxf(MH[128 + q], MH[192 + q]);
#pragma unroll
        for (int g = 0; g < 2; ++g)
#pragma unroll
            for (int r = 0; r < 4; ++r)
                rwm[g * 4 + r] = RelW[q * 33 + g * 16 + quad * 4 + r] - M;
    }

    float lr = 0.f;
    f32x4 oc[4];
#pragma unroll
    for (int i = 0; i < 4; ++i) oc[i] = (f32x4){0.f, 0.f, 0.f, 0.f};

    const __bf16* KpH = Kp + bh * 65536;
    const __bf16* VtH = Vt + bh * 65536;
    __bf16* Pme = Pw + w * 576;            // this wave's 16x36 P tile

    // fragments for tile 0 (K A-operand + V^T A-operand)
    bf16x8 kc[2][2], vc[4];
#pragma unroll
    for (int g = 0; g < 2; ++g)
#pragma unroll
        for (int ch = 0; ch < 2; ++ch)
            kc[g][ch] = *(const bf16x8*)(KpH + (g * 16 + n16) * 64 + ch * 32 + quad * 8);
#pragma unroll
    for (int cn = 0; cn < 4; ++cn)
        vc[cn] = *(const bf16x8*)(VtH + (cn * 16 + n16) * 1024 + quad * 8);

#pragma unroll 2
    for (int kt = 0; kt < 32; ++kt) {
        // issue ALL of tile kt+1's loads now; consumed next iteration
        bf16x8 kn[2][2], vn[4];
        if (kt < 31) {
#pragma unroll
            for (int g = 0; g < 2; ++g)
#pragma unroll
                for (int ch = 0; ch < 2; ++ch)
                    kn[g][ch] = *(const bf16x8*)(KpH + ((kt + 1) * 32 + g * 16 + n16) * 64
                                                 + ch * 32 + quad * 8);
#pragma unroll
            for (int cn = 0; cn < 4; ++cn)
                vn[cn] = *(const bf16x8*)(VtH + (cn * 16 + n16) * 1024
                                          + (kt + 1) * 32 + quad * 8);
        }

        float rh = RelH[q * 33 + kt];

        // S^T = K Q^T : lane gets S[q=n16][key = g*16 + quad*4 + r]
        f32x4 s0 = {0.f, 0.f, 0.f, 0.f}, s1 = s0;
#pragma unroll
        for (int ch = 0; ch < 2; ++ch) {
            s0 = __builtin_amdgcn_mfma_f32_16x16x32_bf16(kc[0][ch], qf[ch], s0, 0, 0, 0);
            s1 = __builtin_amdgcn_mfma_f32_16x16x32_bf16(kc[1][ch], qf[ch], s1, 0, 0, 0);
        }

        // per-lane softmax (static max), P write in B-layout rows
        bf16x4 pb0, pb1;
        float ps = 0.f;
#pragma unroll
        for (int r = 0; r < 4; ++r) {
            float p0 = exp2f(fmaf(s0[r], SCALE2, rh + rwm[r]));
            float p1 = exp2f(fmaf(s1[r], SCALE2, rh + rwm[4 + r]));
            ps += p0 + p1;
            pb0[r] = (__bf16)p0; pb1[r] = (__bf16)p1;
        }
        lr += ps;
        *(bf16x4*)&Pme[n16 * 36 + quad * 4]      = pb0;
        *(bf16x4*)&Pme[n16 * 36 + 16 + quad * 4] = pb1;

        // O^T += V^T P : B-frag = P[q=n16][k=quad*8+j] (same-wave LDS)
        bf16x8 pf = *(const bf16x8*)&Pme[n16 * 36 + quad * 8];
#pragma unroll
        for (int cn = 0; cn < 4; ++cn)
            oc[cn] = __builtin_amdgcn_mfma_f32_16x16x32_bf16(vc[cn], pf, oc[cn], 0, 0, 0);

        if (kt < 31) {
#pragma unroll
            for (int g = 0; g < 2; ++g)
#pragma unroll
                for (int ch = 0; ch < 2; ++ch)
                    kc[g][ch] = kn[g][ch];
#pragma unroll
            for (int cn = 0; cn < 4; ++cn)
                vc[cn] = vn[cn];
        }
    }

    // ---- epilogue: quad-reduce l (lanes differing in bits 4..5), store ----
    lr += __shfl_xor(lr, 16);
    lr += __shfl_xor(lr, 32);
    float inv = 1.f / lr;
    float* orow = outg + base + (sq0 + q) * 1024;
#pragma unroll
    for (int cn = 0; cn < 4; ++cn) {
        f32x4 v = oc[cn];
        v.x *= inv; v.y *= inv; v.z *= inv; v.w *= inv;
        *(f32x4*)(orow + cn * 16 + quad * 4) = v;
    }
}

extern "C" void kernel_launch(void* const* d_in, const int* in_sizes, int n_in,
                              void* d_out, int out_size, void* d_ws, size_t ws_size,
                              hipStream_t stream) {
    (void)in_sizes; (void)n_in; (void)out_size; (void)ws_size;
    const float* q   = (const float*)d_in[0];
    const float* k   = (const float*)d_in[1];
    const float* v   = (const float*)d_in[2];
    const float* rph = (const float*)d_in[3];
    const float* rpw = (const float*)d_in[4];
    __bf16* Kp = (__bf16*)d_ws;                 // 64*1024*64 bf16 = 8 MB
    __bf16* Vt = Kp + 64 * 65536;               // + 8 MB

    dim3 g(16, 64);                             // (key-block / h-pair, bh)
    pack<<<g, 256, 0, stream>>>(k, v, Kp, Vt);
    attn<<<g, 256, 0, stream>>>(q, rph, rpw, Kp, Vt, (float*)d_out);
}